// Round 2
// baseline (786.964 us; speedup 1.0000x reference)
//
#include <hip/hip_runtime.h>

#define HH 384
#define WW 384
#define HWSZ (HH * WW)          // 147456
#define NPLANES 128             // 2 batch * 64 chan
#define NROWS (NPLANES * HH)    // 49152
#define VSTRIPS 8
#define VSTRIP_H (HH / VSTRIPS) // 48
#define NACC 11
#define CHN 64

// ---- Kernel 1: per-row inclusive prefix sums P[row][t] (row-independent) ----
__global__ __launch_bounds__(256) void rowscan_kernel(const float* __restrict__ x,
                                                      float* __restrict__ P) {
    const int lane = threadIdx.x & 63;
    const int wv = threadIdx.x >> 6;
    const int row = blockIdx.x * 4 + wv;          // exact: NROWS/4 blocks
    const float* src = x + (size_t)row * WW + lane * 6;
    float2 a = *(const float2*)(src);
    float2 b = *(const float2*)(src + 2);
    float2 c = *(const float2*)(src + 4);
    float s0 = a.x;
    float s1 = s0 + a.y;
    float s2 = s1 + b.x;
    float s3 = s2 + b.y;
    float s4 = s3 + c.x;
    float s5 = s4 + c.y;
    const float tot = s5;
    float e = tot;
#pragma unroll
    for (int d = 1; d < 64; d <<= 1) {
        float u = __shfl_up(e, d, 64);
        if (lane >= d) e += u;
    }
    e -= tot;                                     // exclusive scan of wave totals
    float* dst = P + (size_t)row * WW + lane * 6;
    float2 o0 = {s0 + e, s1 + e};
    float2 o1 = {s2 + e, s3 + e};
    float2 o2 = {s4 + e, s5 + e};
    *(float2*)(dst) = o0;
    *(float2*)(dst + 2) = o1;
    *(float2*)(dst + 4) = o2;
}

// ---- Kernel 2: vertical running boxsums + moment accumulation (no barriers) ----
__global__ __launch_bounds__(384) void vstats_kernel(const float* __restrict__ P,
                                                     float* __restrict__ partials) {
    const int t = threadIdx.x;          // column
    const int lane = t & 63;
    const int wv = t >> 6;
    const int bid = blockIdx.x;
    const int p = bid >> 3;             // plane
    const int s = bid & 7;              // strip
    const int y0 = s * VSTRIP_H;
    const float* __restrict__ Pp = P + (size_t)p * HWSZ;

    const int W2S[3] = {3, 7, 15};      // l=0->w7, l=1->w15, l=2->w31 (ref order!)
    int hi_i[3], lo_i[3];
    bool lo_ok[3];
    float invcx[3];
#pragma unroll
    for (int i = 0; i < 3; ++i) {
        int w2 = W2S[i];
        int hi = t + w2; if (hi > WW - 1) hi = WW - 1;
        int lo = t - w2 - 1;
        hi_i[i] = hi;
        lo_i[i] = lo < 0 ? 0 : lo;
        lo_ok[i] = lo >= 0;
        int clo = t - w2; if (clo < 0) clo = 0;
        invcx[i] = 1.0f / (float)(hi - clo + 1);
    }

    auto hrow = [&](int r, int i) -> float {
        if ((unsigned)r >= (unsigned)HH) return 0.f;
        const float* row = Pp + (size_t)r * WW;
        float v = row[hi_i[i]];
        float vl = row[lo_i[i]];
        return v - (lo_ok[i] ? vl : 0.f);
    };

    float bsum[3];
#pragma unroll
    for (int i = 0; i < 3; ++i) {
        int w2 = W2S[i];
        float sum = 0.f;
        for (int r = y0 - w2; r <= y0 + w2; ++r) sum += hrow(r, i);
        bsum[i] = sum;
    }

    float Aa[3] = {0.f, 0.f, 0.f};
    float Bb[3] = {0.f, 0.f, 0.f};
    float Cc[3] = {0.f, 0.f, 0.f};
    float T1 = 0.f, T2 = 0.f;

    int y = y0;
    while (true) {
        const float* rowy = Pp + (size_t)y * WW;
        int tm = t > 0 ? t - 1 : 0;
        float ph = rowy[t];
        float pl = rowy[tm];
        float xv = ph - (t > 0 ? pl : 0.f);
        T1 += xv;
        T2 = fmaf(xv, xv, T2);
#pragma unroll
        for (int i = 0; i < 3; ++i) {
            int w2 = W2S[i];
            int chi = y + w2; if (chi > HH - 1) chi = HH - 1;
            int clo = y - w2; if (clo < 0) clo = 0;
            float invcy = __builtin_amdgcn_rcpf((float)(chi - clo + 1));
            float m = bsum[i] * (invcy * invcx[i]);
            Aa[i] += m;
            Bb[i] = fmaf(xv, m, Bb[i]);
            Cc[i] = fmaf(m, m, Cc[i]);
        }
        if (++y >= y0 + VSTRIP_H) break;
#pragma unroll
        for (int i = 0; i < 3; ++i) {
            int w2 = W2S[i];
            bsum[i] += hrow(y + w2, i) - hrow(y - w2 - 1, i);
        }
    }

    float acc[NACC] = {Aa[0], Bb[0], Cc[0], Aa[1], Bb[1], Cc[1],
                       Aa[2], Bb[2], Cc[2], T1, T2};
#pragma unroll
    for (int k = 0; k < NACC; ++k) {
#pragma unroll
        for (int d = 32; d >= 1; d >>= 1) acc[k] += __shfl_xor(acc[k], d, 64);
    }
    __shared__ float redbuf[6 * NACC];
    if (lane == 0) {
#pragma unroll
        for (int k = 0; k < NACC; ++k) redbuf[wv * NACC + k] = acc[k];
    }
    __syncthreads();
    if (t < NACC) {
        float ssum = 0.f;
#pragma unroll
        for (int w = 0; w < 6; ++w) ssum += redbuf[w * NACC + t];
        partials[bid * NACC + t] = ssum;
    }
}

// ---- Kernel 3: per-(plane,l) std -> reciprocal scale ----
__global__ __launch_bounds__(128) void scales_kernel(const float* __restrict__ partials,
                                                     const float* __restrict__ tiny,
                                                     float* __restrict__ scales) {
    int p = threadIdx.x;
    if (p >= NPLANES) return;
    int b = p >> 6, c = p & 63;
    float acc[NACC];
#pragma unroll
    for (int k = 0; k < NACC; ++k) acc[k] = 0.f;
    for (int s = 0; s < VSTRIPS; ++s) {
#pragma unroll
        for (int k = 0; k < NACC; ++k)
            acc[k] += partials[(p * VSTRIPS + s) * NACC + k];
    }
    const float Nf = (float)HWSZ;
    const float invNm1 = 1.0f / (float)(HWSZ - 1);
    float T1 = acc[9], T2 = acc[10];
    float thr = tiny[c] + 1e-6f;
#pragma unroll
    for (int l = 0; l < 4; ++l) {
        float S, Q;
        if (l < 3) {
            S = T1 - acc[l * 3 + 0];
            Q = T2 - 2.f * acc[l * 3 + 1] + acc[l * 3 + 2];
        } else {
            S = T1;     // var(x - mean) == var(x)
            Q = T2;
        }
        float var = (Q - S * S / Nf) * invNm1;
        float sd = sqrtf(fmaxf(var, 0.f));
        sd = fmaxf(sd, thr);
        scales[(b * 4 + l) * CHN + c] = 1.0f / sd;
    }
}

// ---- Kernel 4: out[b,l,c,:,:] = x[b,c,:,:] * scale[b,l,c] ----
__global__ __launch_bounds__(256) void out_kernel(const float* __restrict__ x,
                                                  const float* __restrict__ scales,
                                                  float* __restrict__ out) {
    const unsigned QP = HWSZ / 4;               // 36864 quads per plane
    const unsigned NQ = NPLANES * QP;
    unsigned i = blockIdx.x * blockDim.x + threadIdx.x;
    if (i >= NQ) return;
    unsigned plane = i / QP;
    unsigned q = i - plane * QP;
    unsigned b = plane >> 6, c = plane & 63;
    float4 v = reinterpret_cast<const float4*>(x)[i];
#pragma unroll
    for (int l = 0; l < 4; ++l) {
        float sc = scales[(b * 4 + l) * CHN + c];
        float4 o;
        o.x = v.x * sc; o.y = v.y * sc; o.z = v.z * sc; o.w = v.w * sc;
        reinterpret_cast<float4*>(out)[(size_t)((b * 4 + l) * CHN + c) * QP + q] = o;
    }
}

extern "C" void kernel_launch(void* const* d_in, const int* in_sizes, int n_in,
                              void* d_out, int out_size, void* d_ws, size_t ws_size,
                              hipStream_t stream) {
    const float* x = (const float*)d_in[0];
    const float* tiny = (const float*)d_in[1];
    float* out = (float*)d_out;

    // Reuse d_out as scratch: P (18.87M floats) + partials, both fully consumed
    // before out_kernel overwrites the whole buffer (stream-ordered).
    float* P = out;
    float* partials = out + (size_t)NPLANES * HWSZ;          // 1024*11 floats
    float* scales = (float*)d_ws;                            // 512 floats (tiny)

    rowscan_kernel<<<NROWS / 4, 256, 0, stream>>>(x, P);
    vstats_kernel<<<NPLANES * VSTRIPS, 384, 0, stream>>>(P, partials);
    scales_kernel<<<1, 128, 0, stream>>>(partials, tiny, scales);

    const unsigned NQ = NPLANES * (HWSZ / 4);
    out_kernel<<<(NQ + 255) / 256, 256, 0, stream>>>(x, scales, out);
}

// Round 3
// 211.090 us; speedup vs baseline: 3.7281x; 3.7281x over previous
//
#include <hip/hip_runtime.h>

#define HH 384
#define WW 384
#define HWSZ (HH * WW)          // 147456
#define NPLANES 128             // 2 batch * 64 chan
#define CHN 64
#define VSTRIPS 4
#define STRIP_H 96              // HH / VSTRIPS
#define RING 48                 // LDS ring rows (72 KB) -> single barrier per group safe
#define NACC 11
#define NSUPER 22               // ceil(127 rows / 6); also == compute groups 16 + lag 6

// One block = one (plane, 96-row strip). 6 waves; wave w scans row (group*6+w).
__global__ __launch_bounds__(384, 3) void stats_fused(const float* __restrict__ x,
                                                      float* __restrict__ partials) {
    __shared__ float ring[RING][WW];      // inclusive row prefix sums
    __shared__ float redbuf[6 * NACC];

    const int t = threadIdx.x;            // column 0..383
    const int lane = t & 63;
    const int wv = t >> 6;
    const int bid = blockIdx.x;
    const int p = bid >> 2;               // plane
    const int s = bid & 3;                // strip
    const int y0 = s * STRIP_H;
    const float* __restrict__ xp = x + (size_t)p * HWSZ;

    const int W2S[3] = {3, 7, 15};        // l=0 -> w7, l=1 -> w15, l=2 -> w31
    int hi_i[3], lo_i[3];
    float lomul[3], invcx[3];
#pragma unroll
    for (int i = 0; i < 3; ++i) {
        int w2 = W2S[i];
        int hi = t + w2; if (hi > WW - 1) hi = WW - 1;
        int lo = t - w2 - 1;
        hi_i[i] = hi;
        lo_i[i] = lo < 0 ? 0 : lo;
        lomul[i] = lo < 0 ? 0.f : 1.f;
        int clo = t - w2; if (clo < 0) clo = 0;
        invcx[i] = 1.0f / (float)(hi - clo + 1);
    }

    // horizontal box sum of (zero-padded) row r for window i, from LDS prefix
    auto hrow = [&](int r, int i) -> float {
        if ((unsigned)r >= (unsigned)HH) return 0.f;
        const float* row = ring[(r + RING) % RING];
        return row[hi_i[i]] - row[lo_i[i]] * lomul[i];
    };

    float bsum[3] = {0.f, 0.f, 0.f};      // vertical running box sums (center y)
    float Aa[3] = {0.f, 0.f, 0.f};
    float Bb[3] = {0.f, 0.f, 0.f};
    float Cc[3] = {0.f, 0.f, 0.f};
    float T1 = 0.f, T2 = 0.f;

    // register prefetch of group-0 row (wave-private)
    float2 A0 = {0.f, 0.f}, A1 = {0.f, 0.f}, A2 = {0.f, 0.f};
    {
        int r = y0 - 16 + wv;
        if ((unsigned)r < (unsigned)HH) {
            const float* src = xp + (size_t)r * WW + lane * 6;
            A0 = *(const float2*)(src);
            A1 = *(const float2*)(src + 2);
            A2 = *(const float2*)(src + 4);
        }
    }

    for (int k = 0; k < NSUPER; ++k) {
        int r = y0 - 16 + 6 * k + wv;
        bool valid = (r <= y0 + 110) && ((unsigned)r < (unsigned)HH);
        if (valid) {
            // per-wave independent inclusive scan of row r (6 elems/lane)
            float s0 = A0.x, s1 = s0 + A0.y, s2 = s1 + A1.x;
            float s3 = s2 + A1.y, s4 = s3 + A2.x, s5 = s4 + A2.y;
            float tot = s5, e = tot;
#pragma unroll
            for (int d = 1; d < 64; d <<= 1) {
                float u = __shfl_up(e, d, 64);
                if (lane >= d) e += u;
            }
            e -= tot;                     // exclusive offset of lane totals
            float* dst = &ring[r % RING][lane * 6];
            *(float2*)(dst)     = make_float2(s0 + e, s1 + e);
            *(float2*)(dst + 2) = make_float2(s2 + e, s3 + e);
            *(float2*)(dst + 4) = make_float2(s4 + e, s5 + e);
        }
        // issue next group's loads now; they complete under the compute phase
        if (k < NSUPER - 1) {
            int rn = r + 6;
            if ((rn <= y0 + 110) && ((unsigned)rn < (unsigned)HH)) {
                const float* src = xp + (size_t)rn * WW + lane * 6;
                A0 = *(const float2*)(src);
                A1 = *(const float2*)(src + 2);
                A2 = *(const float2*)(src + 4);
            }
        }
        __syncthreads();                  // single barrier per superiteration

        int j = k - 6;                    // compute group lags staging by 6
        if (j >= 0) {
            if (j == 0) {                 // prime vertical box sums at y = y0
#pragma unroll
                for (int i = 0; i < 3; ++i) {
                    int w2 = W2S[i];
                    float sum = 0.f;
                    for (int rr = y0 - w2; rr <= y0 + w2; ++rr) sum += hrow(rr, i);
                    bsum[i] = sum;
                }
            }
#pragma unroll
            for (int dy = 0; dy < 6; ++dy) {
                int y = y0 + 6 * j + dy;
                if (y > y0) {
#pragma unroll
                    for (int i = 0; i < 3; ++i) {
                        int w2 = W2S[i];
                        bsum[i] += hrow(y + w2, i) - hrow(y - w2 - 1, i);
                    }
                }
                const float* rowy = ring[(y + RING) % RING];
                int tm = t > 0 ? t - 1 : 0;
                float ph = rowy[t];
                float pl = rowy[tm];
                float xv = ph - (t > 0 ? pl : 0.f);   // recover x[y][t]
                T1 += xv;
                T2 = fmaf(xv, xv, T2);
#pragma unroll
                for (int i = 0; i < 3; ++i) {
                    int w2 = W2S[i];
                    int chi = y + w2; if (chi > HH - 1) chi = HH - 1;
                    int clo = y - w2; if (clo < 0) clo = 0;
                    float invcy = __builtin_amdgcn_rcpf((float)(chi - clo + 1));
                    float m = bsum[i] * (invcy * invcx[i]);
                    Aa[i] += m;
                    Bb[i] = fmaf(xv, m, Bb[i]);
                    Cc[i] = fmaf(m, m, Cc[i]);
                }
            }
        }
    }

    // deterministic block reduction of 11 accumulators
    float acc[NACC] = {Aa[0], Bb[0], Cc[0], Aa[1], Bb[1], Cc[1],
                       Aa[2], Bb[2], Cc[2], T1, T2};
#pragma unroll
    for (int q = 0; q < NACC; ++q) {
#pragma unroll
        for (int d = 32; d >= 1; d >>= 1) acc[q] += __shfl_xor(acc[q], d, 64);
    }
    if (lane == 0) {
#pragma unroll
        for (int q = 0; q < NACC; ++q) redbuf[wv * NACC + q] = acc[q];
    }
    __syncthreads();
    if (t < NACC) {
        float ssum = 0.f;
#pragma unroll
        for (int w = 0; w < 6; ++w) ssum += redbuf[w * NACC + t];
        partials[bid * NACC + t] = ssum;
    }
}

// ---- per-(plane, l) std -> reciprocal scale ----
__global__ __launch_bounds__(128) void scales_kernel(const float* __restrict__ partials,
                                                     const float* __restrict__ tiny,
                                                     float* __restrict__ scales) {
    int p = threadIdx.x;
    if (p >= NPLANES) return;
    int b = p >> 6, c = p & 63;
    float acc[NACC];
#pragma unroll
    for (int q = 0; q < NACC; ++q) acc[q] = 0.f;
    for (int s = 0; s < VSTRIPS; ++s) {
#pragma unroll
        for (int q = 0; q < NACC; ++q)
            acc[q] += partials[(p * VSTRIPS + s) * NACC + q];
    }
    const float Nf = (float)HWSZ;
    const float invNm1 = 1.0f / (float)(HWSZ - 1);
    float T1 = acc[9], T2 = acc[10];
    float thr = tiny[c] + 1e-6f;
#pragma unroll
    for (int l = 0; l < 4; ++l) {
        float S, Q;
        if (l < 3) {
            S = T1 - acc[l * 3 + 0];
            Q = T2 - 2.f * acc[l * 3 + 1] + acc[l * 3 + 2];
        } else {
            S = T1;     // var(x - mean(x)) == var(x)
            Q = T2;
        }
        float var = (Q - S * S / Nf) * invNm1;
        float sd = sqrtf(fmaxf(var, 0.f));
        sd = fmaxf(sd, thr);
        scales[(b * 4 + l) * CHN + c] = 1.0f / sd;
    }
}

// ---- out[b,l,c,:,:] = x[b,c,:,:] * scale[b,l,c] ----
__global__ __launch_bounds__(256) void out_kernel(const float* __restrict__ x,
                                                  const float* __restrict__ scales,
                                                  float* __restrict__ out) {
    const unsigned QP = HWSZ / 4;               // 36864 quads per plane
    const unsigned NQ = NPLANES * QP;
    unsigned i = blockIdx.x * blockDim.x + threadIdx.x;
    if (i >= NQ) return;
    unsigned plane = i / QP;
    unsigned q = i - plane * QP;
    unsigned b = plane >> 6, c = plane & 63;
    float4 v = reinterpret_cast<const float4*>(x)[i];
#pragma unroll
    for (int l = 0; l < 4; ++l) {
        float sc = scales[(b * 4 + l) * CHN + c];
        float4 o;
        o.x = v.x * sc; o.y = v.y * sc; o.z = v.z * sc; o.w = v.w * sc;
        reinterpret_cast<float4*>(out)[(size_t)((b * 4 + l) * CHN + c) * QP + q] = o;
    }
}

extern "C" void kernel_launch(void* const* d_in, const int* in_sizes, int n_in,
                              void* d_out, int out_size, void* d_ws, size_t ws_size,
                              hipStream_t stream) {
    const float* x = (const float*)d_in[0];
    const float* tiny = (const float*)d_in[1];
    float* out = (float*)d_out;

    float* partials = (float*)d_ws;                              // 512*11 floats
    float* scales = partials + NPLANES * VSTRIPS * NACC;         // 512 floats

    stats_fused<<<NPLANES * VSTRIPS, 384, 0, stream>>>(x, partials);
    scales_kernel<<<1, 128, 0, stream>>>(partials, tiny, scales);

    const unsigned NQ = NPLANES * (HWSZ / 4);
    out_kernel<<<(NQ + 255) / 256, 256, 0, stream>>>(x, scales, out);
}